// Round 10
// baseline (126.646 us; speedup 1.0000x reference)
//
#include <hip/hip_runtime.h>
#include <stdint.h>

#define BSZ  4
#define NSEQ 2048
#define DM   128
#define NH   8
#define DK   16
#define LOG2E 1.4426950408889634f
// LOG2E / sqrt(128): folded into Wq/bq so scores exit QK^T in log2 domain
#define SCALE_QL 0.1275156338341935f
// mask weight: w = mask * 2^-18 (exact in bf16); folded into V' and the
// l-row of the PV A-tile. p = exp2(S) stays <= ~2^10, l ~ 1e-2 -> safe fp32.
#define W_SCALE 3.814697265625e-6f

typedef __bf16          bf16x8v __attribute__((ext_vector_type(8)));
typedef float           f32x4   __attribute__((ext_vector_type(4)));
typedef float           f32x16  __attribute__((ext_vector_type(16)));
typedef unsigned short  u16x8   __attribute__((ext_vector_type(8)));
typedef unsigned short  u16x4   __attribute__((ext_vector_type(4)));
typedef unsigned int    u32x2   __attribute__((ext_vector_type(2)));
typedef unsigned int    u32x4   __attribute__((ext_vector_type(4)));

__device__ __forceinline__ unsigned short f2bf(float f) {
    unsigned u = __float_as_uint(f);
    u = (u + 0x7fffu + ((u >> 16) & 1u)) >> 16;
    return (unsigned short)u;
}

__device__ __forceinline__ unsigned int pack2bf(float a, float b) {
#if __has_builtin(__builtin_amdgcn_cvt_pk_bf16_f32)
    typedef __bf16 bf16x2 __attribute__((ext_vector_type(2)));
    bf16x2 v = __builtin_amdgcn_cvt_pk_bf16_f32(a, b);
    return __builtin_bit_cast(unsigned int, v);
#else
    return (unsigned)f2bf(a) | ((unsigned)f2bf(b) << 16);
#endif
}

__device__ __forceinline__ float exp2_(float x) {
#if __has_builtin(__builtin_amdgcn_exp2f)
    return __builtin_amdgcn_exp2f(x);
#else
    return exp2f(x);
#endif
}

__device__ __forceinline__ f32x4 mfma16(u16x8 a, u16x8 b, f32x4 c) {
    return __builtin_amdgcn_mfma_f32_16x16x32_bf16(
        __builtin_bit_cast(bf16x8v, a), __builtin_bit_cast(bf16x8v, b), c, 0, 0, 0);
}
__device__ __forceinline__ f32x16 mfma32(u16x8 a, u16x8 b, f32x16 c) {
    return __builtin_amdgcn_mfma_f32_32x32x16_bf16(
        __builtin_bit_cast(bf16x8v, a), __builtin_bit_cast(bf16x8v, b), c, 0, 0, 0);
}

// ROUND-9 (kept): shuffle-free P->B-frag. Packing S regs 0..7 / 8..15
// straight into B-frags induces the fixed k-slot->kv involution
//   rho = [0,1,2,3, 8,9,10,11, 4,5,6,7, 12,13,14,15]
// which is pre-absorbed into the PV A-tile by k_qkv/k_prep.
// ROUND-10: exp2 and pack fused into one helper (one stream at a time ->
// only 16 S-regs live; register discipline for the software pipeline).
__device__ __forceinline__ void exppack(f32x16 S, u16x8& b1, u16x8& b2) {
#pragma unroll
    for (int i = 0; i < 16; ++i) S[i] = exp2_(S[i]);
    const u32x4 f1 = {pack2bf(S[0],  S[1]),  pack2bf(S[2],  S[3]),
                      pack2bf(S[4],  S[5]),  pack2bf(S[6],  S[7])};
    const u32x4 f2 = {pack2bf(S[8],  S[9]),  pack2bf(S[10], S[11]),
                      pack2bf(S[12], S[13]), pack2bf(S[14], S[15])};
    b1 = __builtin_bit_cast(u16x8, f1);
    b2 = __builtin_bit_cast(u16x8, f2);
}

// ---------------------------------------------------------------------------
// k_prep: one-shot weight conversion + mask weave. Converts Wq (pre-scaled
// to log2 domain), Wk, Wv, Wfc to bf16 once, and weaves w = bf16(mask*2^-18)
// into VW2 row 16 at rho-permuted k-slots. grid = 96 x 256.
// ---------------------------------------------------------------------------
__global__ __launch_bounds__(256) void k_prep(
    const float* __restrict__ Wq, const float* __restrict__ Wk,
    const float* __restrict__ Wv, const float* __restrict__ Wfc,
    const float* __restrict__ mask,
    unsigned short* __restrict__ WqB, unsigned short* __restrict__ WkB,
    unsigned short* __restrict__ WvB, unsigned short* __restrict__ WfcB,
    unsigned short* __restrict__ VW2)
{
    const int gt = blockIdx.x * 256 + threadIdx.x;
    if (gt < DM * DM) {
        WqB[gt]  = f2bf(Wq[gt] * SCALE_QL);
        WkB[gt]  = f2bf(Wk[gt]);
        WvB[gt]  = f2bf(Wv[gt]);
        WfcB[gt] = f2bf(Wfc[gt]);
    } else if (gt < DM * DM + BSZ * NSEQ) {
        const int i  = gt - DM * DM;          // i = b*NSEQ + kv
        const int kv = i & (NSEQ - 1);
        const int bb = i >> 11;
        const unsigned short w16 = f2bf(mask[i] * W_SCALE);
        // rho-permuted k-slot: khalf=(kv>>2)&1, j=(kv&3)+4*((kv>>3)&1)
        unsigned short* dst = VW2 +
            (((size_t)(bb * NH) * 128 + (kv >> 4)) << 9) +
            (16 + ((kv >> 2) & 1) * 32) * 8 + (kv & 3) + 4 * ((kv >> 3) & 1);
#pragma unroll
        for (int hh = 0; hh < NH; ++hh)
            dst[(size_t)hh * 128 * 512] = w16;
    }
}

// ---------------------------------------------------------------------------
// k_qkv: C^T-form projection, x-tile staged in LDS (coalesced f32x4 loads).
// grid = b(4) x n-tile32(64), 768 threads = 12 waves = mat(3) x nsub(2) x th(2).
// W pre-converted bf16 (k_prep). Q,K -> [B][H][N][16] bf16.
// V is emitted directly as the PV A-tile VW2[bh][g=kv/16][lane][8] with the
// rho column permutation: k-slot of column o: khalf=(o>>2)&1 (lane =
// row + 32*khalf), j=(o&3)+4*((o>>3)&1). Rows 0-15 = V' (V scaled by
// w=mask*2^-18), row 16 = w (k_prep), rows 17-31 = garbage (C rows unread).
// ---------------------------------------------------------------------------
__global__ __launch_bounds__(768) void k_qkv(
    const float* __restrict__ x,
    const unsigned short* __restrict__ WqB, const float* __restrict__ bq,
    const unsigned short* __restrict__ WkB, const float* __restrict__ bk,
    const unsigned short* __restrict__ WvB, const float* __restrict__ bv,
    const float* __restrict__ mask,
    unsigned short* __restrict__ Q, unsigned short* __restrict__ Kb,
    unsigned short* __restrict__ VW2)
{
    __shared__ __align__(16) float xs[DM * 36];   // 32 n + 4 pad
    const int tid = threadIdx.x;

    const int b  = blockIdx.x >> 6;
    const int n0 = (blockIdx.x & 63) << 5;

    // stage x[b][0..128][n0..n0+32] -> xs[d*36 + j], fully coalesced
#pragma unroll
    for (int i = tid; i < 1024; i += 768) {
        const int d = i >> 3, c4 = (i & 7) << 2;
        *reinterpret_cast<f32x4*>(&xs[d * 36 + c4]) =
            *reinterpret_cast<const f32x4*>(x + (size_t)(b * DM + d) * NSEQ + n0 + c4);
    }
    __syncthreads();

    const int lane = tid & 63;
    const int wv   = tid >> 6;          // 0..11
    const int mat  = wv >> 2;           // 0..2
    const int nt   = (wv >> 1) & 1;     // n subtile
    const int th   = wv & 1;            // t half
    const int c    = lane & 15;
    const int quad = lane >> 4;
    const int col  = n0 + nt * 16 + c;

    // B-frag from LDS: B[k=d][n=c]
    u16x8 xf[4];
#pragma unroll
    for (int kk = 0; kk < 4; ++kk) {
        float f[8];
#pragma unroll
        for (int j = 0; j < 8; ++j)
            f[j] = xs[(kk * 32 + quad * 8 + j) * 36 + nt * 16 + c];
        u32x4 u = {pack2bf(f[0], f[1]), pack2bf(f[2], f[3]),
                   pack2bf(f[4], f[5]), pack2bf(f[6], f[7])};
        xf[kk] = __builtin_bit_cast(u16x8, u);
    }

    const unsigned short* W = (mat == 0) ? WqB : (mat == 1) ? WkB : WvB;
    const float* bias = (mat == 0) ? bq : (mat == 1) ? bk : bv;
    const float  sc   = (mat == 0) ? SCALE_QL : 1.0f;   // bias scale only
    // V' scale: w = mask * 2^-18 for this column
    const float  vwsc = (mat == 2) ? mask[b * NSEQ + col] * W_SCALE : 0.f;
    const int    g    = col >> 4;
    // rho-permuted k-slot for kv-column col
    const int    roff = ((col >> 2) & 1) * 32;
    const int    j7   = (col & 3) | (((col >> 3) & 1) << 2);

#pragma unroll
    for (int tt = 0; tt < 4; ++tt) {
        const int t = th * 4 + tt;
        f32x4 acc = {0.f, 0.f, 0.f, 0.f};
#pragma unroll
        for (int kk = 0; kk < 4; ++kk)
            acc = mfma16(*reinterpret_cast<const u16x8*>(
                             W + (t * 16 + c) * DM + kk * 32 + quad * 8),
                         xf[kk], acc);
        if (mat == 2) {
            unsigned short* vwp = VW2 +
                (((size_t)((b * NH + t) * 128 + g)) << 9) + j7;
#pragma unroll
            for (int r = 0; r < 4; ++r)
                vwp[(quad * 4 + r + roff) * 8] =
                    f2bf((acc[r] + bias[t * 16 + quad * 4 + r]) * vwsc);
        } else {
            u16x4 pk;
#pragma unroll
            for (int r = 0; r < 4; ++r)
                pk[r] = f2bf(acc[r] + bias[t * 16 + quad * 4 + r] * sc);
            *reinterpret_cast<u16x4*>(
                (mat == 0 ? Q : Kb) + ((size_t)(b * NH + t) * NSEQ + col) * DK +
                quad * 4) = pk;
        }
    }
}

// ---------------------------------------------------------------------------
// k_attn: fixed-scale flash attention, register-resident main loop.
// ROUND-10 CHANGE: SOFTWARE-PIPELINED BY ONE STAGE. 16 stages of 32 kv;
// in stage s the wave (1) issues QK-MFMA for stage s+1, (2) runs PV(s)
// with B-frags packed LAST stage (ready - no dependency wait), (3)
// exp2/packs stage s+1's S under the PV MFMAs, (4) refills nk (2-stage
// prefetch) and va (1-stage). The old serial chain QK->exp2->pack->PV per
// stage becomes max(MFMA cluster, VALU cluster). Register discipline:
// streams processed A-then-B so only 16 S-regs live (round-2 spill lesson);
// peak liveness ~110 < 128 at (256,4).
// rho-absorbed A-tile (round 9): zero DS ops, zero shuffles in the loop.
// Two query-tiles per block (round 8): grid 1024 = 4 blocks/CU, shared
// nk/va across streams. l falls out of PV C-row 16 (w row in A-tile).
// LDS (21.5 KB) only for the epilogue merge. Tripwire: WRITE_SIZE.
// ---------------------------------------------------------------------------
__global__ __launch_bounds__(256, 4) void k_attn(
    const unsigned short* __restrict__ Q,
    const unsigned short* __restrict__ Kb,
    const unsigned short* __restrict__ VW2,
    unsigned short* __restrict__ AO)
{
    __shared__ __align__(16) float smem[256 + 2 * 4 * 32 * 20];  // Lsm + Osm
    const int tid  = threadIdx.x;
    const int lane = tid & 63;
    const int w    = tid >> 6;      // kv quarter
    const int q32  = lane & 31;
    const int hi   = lane >> 5;

    // XCD-chunked swizzle: 1024 blocks -> 128-block chunk per XCD
    const int bid = ((int)blockIdx.x & 7) * 128 + ((int)blockIdx.x >> 3);
    const int b  = bid >> 8;
    const int h  = (bid >> 5) & 7;
    const int n0 = (bid & 31) << 6;     // 64-query tile
    const int bh = b * NH + h;

    // Q B-frags for the two 32-query sub-tiles (prescaled to log2 domain)
    const u16x8 uqA = *reinterpret_cast<const u16x8*>(
        Q + ((size_t)bh * NSEQ + n0 + q32) * DK + 8 * hi);
    const u16x8 uqB = *reinterpret_cast<const u16x8*>(
        Q + ((size_t)bh * NSEQ + n0 + 32 + q32) * DK + 8 * hi);

    const unsigned short* Kp = Kb + (size_t)bh * NSEQ * DK + 8 * hi;
    const unsigned short* Ap = VW2 + (((size_t)bh * 128) << 9) + lane * 8;

    f32x16 accA = {};                 // O^T rows 0-15, l at row 16 (tile A)
    f32x16 accB = {};                 // (tile B)
    const f32x16 z16 = {};
    const int kvb = w * (NSEQ / 4);   // 512-kv quarter
    const int gb  = kvb >> 4;         // first group of this quarter

    // ---- pipeline prologue: nk for blocks 0/1, bf + va for stage 0 ----
    u16x8 nkE = *reinterpret_cast<const u16x8*>(Kp + (size_t)(kvb + q32) * DK);
    u16x8 nkO = *reinterpret_cast<const u16x8*>(Kp + (size_t)(kvb + 32 + q32) * DK);
    u16x8 bfEA1, bfEA2, bfEB1, bfEB2;  // stage-s (even) B-frags
    u16x8 vaE0, vaE1;                  // stage-s (even) A-frags
    {
        __builtin_amdgcn_s_setprio(1);
        f32x16 SA = mfma32(nkE, uqA, z16);
        f32x16 SB = mfma32(nkE, uqB, z16);
        __builtin_amdgcn_s_setprio(0);
        nkE = *reinterpret_cast<const u16x8*>(Kp + (size_t)(kvb + 64 + q32) * DK);
        exppack(SA, bfEA1, bfEA2);
        exppack(SB, bfEB1, bfEB2);
    }
    vaE0 = *reinterpret_cast<const u16x8*>(Ap + ((size_t)gb << 9));
    vaE1 = *reinterpret_cast<const u16x8*>(Ap + ((size_t)(gb + 1) << 9));

#pragma unroll 1
    for (int it = 0; it < 8; ++it) {
        const int kvs = kvb + it * 64;     // even stage (s=2it) kv base
        const int g0  = gb + it * 4;       // even stage group

        // ===== even stage s=2it: QK(s+1) || PV(s), then pack(s+1) =====
        u16x8 bfOA1, bfOA2, bfOB1, bfOB2, vaO0, vaO1;
        {
            __builtin_amdgcn_s_setprio(1);
            f32x16 SA = mfma32(nkO, uqA, z16);     // QK stage s+1 (block 2it+1)
            accA = mfma32(vaE0, bfEA1, accA);      // PV stage s
            accB = mfma32(vaE0, bfEB1, accB);
            accA = mfma32(vaE1, bfEA2, accA);
            accB = mfma32(vaE1, bfEB2, accB);
            __builtin_amdgcn_s_setprio(0);
            exppack(SA, bfOA1, bfOA2);
            __builtin_amdgcn_s_setprio(1);
            f32x16 SB = mfma32(nkO, uqB, z16);
            __builtin_amdgcn_s_setprio(0);
            if (it < 7)                            // refill block 2it+3
                nkO = *reinterpret_cast<const u16x8*>(
                    Kp + (size_t)(kvs + 96 + q32) * DK);
            exppack(SB, bfOB1, bfOB2);
            vaO0 = *reinterpret_cast<const u16x8*>(Ap + ((size_t)(g0 + 2) << 9));
            vaO1 = *reinterpret_cast<const u16x8*>(Ap + ((size_t)(g0 + 3) << 9));
        }

        // ===== odd stage s=2it+1: QK(s+1) || PV(s), then pack(s+1) =====
        {
            __builtin_amdgcn_s_setprio(1);
            f32x16 SA;
            if (it < 7) SA = mfma32(nkE, uqA, z16); // QK stage s+1 (block 2it+2)
            accA = mfma32(vaO0, bfOA1, accA);       // PV stage s
            accB = mfma32(vaO0, bfOB1, accB);
            accA = mfma32(vaO1, bfOA2, accA);
            accB = mfma32(vaO1, bfOB2, accB);
            __builtin_amdgcn_s_setprio(0);
            if (it < 7) {
                exppack(SA, bfEA1, bfEA2);
                __builtin_amdgcn_s_setprio(1);
                f32x16 SB = mfma32(nkE, uqB, z16);
                __builtin_amdgcn_s_setprio(0);
                if (it < 6)                         // refill block 2it+4
                    nkE = *reinterpret_cast<const u16x8*>(
                        Kp + (size_t)(kvs + 128 + q32) * DK);
                exppack(SB, bfEB1, bfEB2);
                vaE0 = *reinterpret_cast<const u16x8*>(Ap + ((size_t)(g0 + 4) << 9));
                vaE1 = *reinterpret_cast<const u16x8*>(Ap + ((size_t)(g0 + 5) << 9));
            }
        }
    }

    // ---- 4-wave merge, two tiles ----
    // acc layout: col q=q32; hi=0 regs: dk 0-3 (r0-3), dk 8-11 (r4-7), l (r8)
    //             hi=1 regs: dk 4-7 (r0-3), dk 12-15 (r4-7)
    float* Lsm = smem;            // [t2][w][32]
    float* Osm = smem + 256;      // [t2][w][q*20 + dk], tile stride 2560
    {
        float* Orow = Osm + w * 640 + q32 * 20;
        *reinterpret_cast<f32x4*>(Orow + (hi ? 4 : 0)) =
            f32x4{accA[0], accA[1], accA[2], accA[3]};
        *reinterpret_cast<f32x4*>(Orow + (hi ? 12 : 8)) =
            f32x4{accA[4], accA[5], accA[6], accA[7]};
        if (!hi) Lsm[w * 32 + q32] = accA[8];
        float* Orow2 = Orow + 2560;
        *reinterpret_cast<f32x4*>(Orow2 + (hi ? 4 : 0)) =
            f32x4{accB[0], accB[1], accB[2], accB[3]};
        *reinterpret_cast<f32x4*>(Orow2 + (hi ? 12 : 8)) =
            f32x4{accB[4], accB[5], accB[6], accB[7]};
        if (!hi) Lsm[128 + w * 32 + q32] = accB[8];
    }
    __syncthreads();

    const int q   = tid >> 3;              // 0..31
    const int dk2 = (tid & 7) * 2;         // 0,2,..,14
#pragma unroll
    for (int t2 = 0; t2 < 2; ++t2) {
        const float* Lt = Lsm + t2 * 128;
        const float l = Lt[q] + Lt[32 + q] + Lt[64 + q] + Lt[96 + q];
        const float* Oq = Osm + t2 * 2560 + q * 20 + dk2;
        const float v0 = Oq[0] + Oq[640] + Oq[1280] + Oq[1920];
        const float v1 = Oq[1] + Oq[641] + Oq[1281] + Oq[1921];
        const float inv = 1.0f / l;
        *reinterpret_cast<unsigned int*>(
            AO + ((size_t)(b * NSEQ) + n0 + t2 * 32 + q) * DM + h * DK + dk2) =
            pack2bf(v0 * inv, v1 * inv);
    }
}

// ---------------------------------------------------------------------------
// k_fc: C^T-form FC, output directly in (B, D, N).
// grid = b(4) x n-tile(128) x t-half(2), 4 waves, wave = one d'-tile.
// ---------------------------------------------------------------------------
__global__ __launch_bounds__(256) void k_fc(
    const unsigned short* __restrict__ AO,
    const unsigned short* __restrict__ WfcB, const float* __restrict__ bfc,
    float* __restrict__ out)
{
    const int lane = threadIdx.x & 63;
    const int w    = threadIdx.x >> 6;
    const int c    = lane & 15;
    const int quad = lane >> 4;
    const int b    = blockIdx.x >> 8;
    const int n0   = ((blockIdx.x >> 1) & 127) << 4;
    const int t    = (blockIdx.x & 1) * 4 + w;

    u16x8 af[4];
#pragma unroll
    for (int kk = 0; kk < 4; ++kk)
        af[kk] = *reinterpret_cast<const u16x8*>(
            AO + ((size_t)(b * NSEQ) + n0 + c) * DM + kk * 32 + quad * 8);

    f32x4 acc = {0.f, 0.f, 0.f, 0.f};
#pragma unroll
    for (int kk = 0; kk < 4; ++kk)
        acc = mfma16(*reinterpret_cast<const u16x8*>(
                         WfcB + (t * 16 + c) * DM + kk * 32 + quad * 8),
                     af[kk], acc);
#pragma unroll
    for (int r = 0; r < 4; ++r)
        out[(size_t)(b * DM + t * 16 + quad * 4 + r) * NSEQ + n0 + c] =
            acc[r] + bfc[t * 16 + quad * 4 + r];
}

// ---------------------------------------------------------------------------
extern "C" void kernel_launch(void* const* d_in, const int* in_sizes, int n_in,
                              void* d_out, int out_size, void* d_ws, size_t ws_size,
                              hipStream_t stream)
{
    const float* x    = (const float*)d_in[0];
    const float* mask = (const float*)d_in[1];
    const float* Wq   = (const float*)d_in[2];
    const float* bq   = (const float*)d_in[3];
    const float* Wk   = (const float*)d_in[4];
    const float* bk   = (const float*)d_in[5];
    const float* Wv   = (const float*)d_in[6];
    const float* bv   = (const float*)d_in[7];
    const float* Wfc  = (const float*)d_in[8];
    const float* bfc  = (const float*)d_in[9];
    float* out = (float*)d_out;

    const size_t QKV_ELEMS = (size_t)BSZ * NH * NSEQ * DK;  // 1,048,576
    unsigned short* Q    = (unsigned short*)d_ws;
    unsigned short* Kb   = Q + QKV_ELEMS;
    unsigned short* AO   = Kb + QKV_ELEMS;
    unsigned short* WfcB = AO + QKV_ELEMS;
    unsigned short* VW2  = WfcB + DM * DM;   // [bh][g=128][lane=64][8] bf16
    unsigned short* WqB  = VW2 + (size_t)BSZ * NH * 128 * 512;
    unsigned short* WkB  = WqB + DM * DM;
    unsigned short* WvB  = WkB + DM * DM;

    k_prep<<<96, 256, 0, stream>>>(Wq, Wk, Wv, Wfc, mask,
                                   WqB, WkB, WvB, WfcB, VW2);
    k_qkv<<<256, 768, 0, stream>>>(x, WqB, bq, WkB, bk, WvB, bv, mask,
                                   Q, Kb, VW2);
    k_attn<<<1024, 256, 0, stream>>>(Q, Kb, VW2, AO);
    k_fc<<<1024, 256, 0, stream>>>(AO, WfcB, bfc, out);
}

// Round 11
// 118.125 us; speedup vs baseline: 1.0721x; 1.0721x over previous
//
#include <hip/hip_runtime.h>
#include <stdint.h>

#define BSZ  4
#define NSEQ 2048
#define DM   128
#define NH   8
#define DK   16
#define LOG2E 1.4426950408889634f
// LOG2E / sqrt(128): folded into Wq/bq so scores exit QK^T in log2 domain
#define SCALE_QL 0.1275156338341935f
// mask weight: w = mask * 2^-18 (exact in bf16); folded into V' and the
// l-row of the PV A-tile. p = exp2(S) stays <= ~2^10, l ~ 1e-2 -> safe fp32.
#define W_SCALE 3.814697265625e-6f

typedef __bf16          bf16x8v __attribute__((ext_vector_type(8)));
typedef float           f32x4   __attribute__((ext_vector_type(4)));
typedef float           f32x16  __attribute__((ext_vector_type(16)));
typedef unsigned short  u16x8   __attribute__((ext_vector_type(8)));
typedef unsigned short  u16x4   __attribute__((ext_vector_type(4)));
typedef unsigned int    u32x2   __attribute__((ext_vector_type(2)));
typedef unsigned int    u32x4   __attribute__((ext_vector_type(4)));

__device__ __forceinline__ unsigned short f2bf(float f) {
    unsigned u = __float_as_uint(f);
    u = (u + 0x7fffu + ((u >> 16) & 1u)) >> 16;
    return (unsigned short)u;
}

__device__ __forceinline__ unsigned int pack2bf(float a, float b) {
#if __has_builtin(__builtin_amdgcn_cvt_pk_bf16_f32)
    typedef __bf16 bf16x2 __attribute__((ext_vector_type(2)));
    bf16x2 v = __builtin_amdgcn_cvt_pk_bf16_f32(a, b);
    return __builtin_bit_cast(unsigned int, v);
#else
    return (unsigned)f2bf(a) | ((unsigned)f2bf(b) << 16);
#endif
}

__device__ __forceinline__ float exp2_(float x) {
#if __has_builtin(__builtin_amdgcn_exp2f)
    return __builtin_amdgcn_exp2f(x);
#else
    return exp2f(x);
#endif
}

__device__ __forceinline__ f32x4 mfma16(u16x8 a, u16x8 b, f32x4 c) {
    return __builtin_amdgcn_mfma_f32_16x16x32_bf16(
        __builtin_bit_cast(bf16x8v, a), __builtin_bit_cast(bf16x8v, b), c, 0, 0, 0);
}
__device__ __forceinline__ f32x16 mfma32(u16x8 a, u16x8 b, f32x16 c) {
    return __builtin_amdgcn_mfma_f32_32x32x16_bf16(
        __builtin_bit_cast(bf16x8v, a), __builtin_bit_cast(bf16x8v, b), c, 0, 0, 0);
}

// ROUND-9 (kept): shuffle-free P->B-frag. Packing S regs 0..7 / 8..15
// straight into B-frags induces the fixed k-slot->kv involution
//   rho = [0,1,2,3, 8,9,10,11, 4,5,6,7, 12,13,14,15]
// which is pre-absorbed into the PV A-tile by k_qkv/k_prep.
__device__ __forceinline__ void exppack(f32x16 S, u16x8& b1, u16x8& b2) {
#pragma unroll
    for (int i = 0; i < 16; ++i) S[i] = exp2_(S[i]);
    const u32x4 f1 = {pack2bf(S[0],  S[1]),  pack2bf(S[2],  S[3]),
                      pack2bf(S[4],  S[5]),  pack2bf(S[6],  S[7])};
    const u32x4 f2 = {pack2bf(S[8],  S[9]),  pack2bf(S[10], S[11]),
                      pack2bf(S[12], S[13]), pack2bf(S[14], S[15])};
    b1 = __builtin_bit_cast(u16x8, f1);
    b2 = __builtin_bit_cast(u16x8, f2);
}

// ---------------------------------------------------------------------------
// k_prep: one-shot weight conversion + mask weave. Converts Wq (pre-scaled
// to log2 domain), Wk, Wv, Wfc to bf16 once, and weaves w = bf16(mask*2^-18)
// into VW2 row 16 at rho-permuted k-slots. grid = 96 x 256.
// ---------------------------------------------------------------------------
__global__ __launch_bounds__(256) void k_prep(
    const float* __restrict__ Wq, const float* __restrict__ Wk,
    const float* __restrict__ Wv, const float* __restrict__ Wfc,
    const float* __restrict__ mask,
    unsigned short* __restrict__ WqB, unsigned short* __restrict__ WkB,
    unsigned short* __restrict__ WvB, unsigned short* __restrict__ WfcB,
    unsigned short* __restrict__ VW2)
{
    const int gt = blockIdx.x * 256 + threadIdx.x;
    if (gt < DM * DM) {
        WqB[gt]  = f2bf(Wq[gt] * SCALE_QL);
        WkB[gt]  = f2bf(Wk[gt]);
        WvB[gt]  = f2bf(Wv[gt]);
        WfcB[gt] = f2bf(Wfc[gt]);
    } else if (gt < DM * DM + BSZ * NSEQ) {
        const int i  = gt - DM * DM;          // i = b*NSEQ + kv
        const int kv = i & (NSEQ - 1);
        const int bb = i >> 11;
        const unsigned short w16 = f2bf(mask[i] * W_SCALE);
        // rho-permuted k-slot: khalf=(kv>>2)&1, j=(kv&3)+4*((kv>>3)&1)
        unsigned short* dst = VW2 +
            (((size_t)(bb * NH) * 128 + (kv >> 4)) << 9) +
            (16 + ((kv >> 2) & 1) * 32) * 8 + (kv & 3) + 4 * ((kv >> 3) & 1);
#pragma unroll
        for (int hh = 0; hh < NH; ++hh)
            dst[(size_t)hh * 128 * 512] = w16;
    }
}

// ---------------------------------------------------------------------------
// k_qkv: C^T-form projection, x-tile staged in LDS (coalesced f32x4 loads).
// grid = b(4) x n-tile32(64), 768 threads = 12 waves = mat(3) x nsub(2) x th(2).
// W pre-converted bf16 (k_prep). Q,K -> [B][H][N][16] bf16.
// V is emitted directly as the PV A-tile VW2[bh][g=kv/16][lane][8] with the
// rho column permutation: k-slot of column o: khalf=(o>>2)&1 (lane =
// row + 32*khalf), j=(o&3)+4*((o>>3)&1). Rows 0-15 = V' (V scaled by
// w=mask*2^-18), row 16 = w (k_prep), rows 17-31 = garbage (C rows unread).
// ---------------------------------------------------------------------------
__global__ __launch_bounds__(768) void k_qkv(
    const float* __restrict__ x,
    const unsigned short* __restrict__ WqB, const float* __restrict__ bq,
    const unsigned short* __restrict__ WkB, const float* __restrict__ bk,
    const unsigned short* __restrict__ WvB, const float* __restrict__ bv,
    const float* __restrict__ mask,
    unsigned short* __restrict__ Q, unsigned short* __restrict__ Kb,
    unsigned short* __restrict__ VW2)
{
    __shared__ __align__(16) float xs[DM * 36];   // 32 n + 4 pad
    const int tid = threadIdx.x;

    const int b  = blockIdx.x >> 6;
    const int n0 = (blockIdx.x & 63) << 5;

    // stage x[b][0..128][n0..n0+32] -> xs[d*36 + j], fully coalesced
#pragma unroll
    for (int i = tid; i < 1024; i += 768) {
        const int d = i >> 3, c4 = (i & 7) << 2;
        *reinterpret_cast<f32x4*>(&xs[d * 36 + c4]) =
            *reinterpret_cast<const f32x4*>(x + (size_t)(b * DM + d) * NSEQ + n0 + c4);
    }
    __syncthreads();

    const int lane = tid & 63;
    const int wv   = tid >> 6;          // 0..11
    const int mat  = wv >> 2;           // 0..2
    const int nt   = (wv >> 1) & 1;     // n subtile
    const int th   = wv & 1;            // t half
    const int c    = lane & 15;
    const int quad = lane >> 4;
    const int col  = n0 + nt * 16 + c;

    // B-frag from LDS: B[k=d][n=c]
    u16x8 xf[4];
#pragma unroll
    for (int kk = 0; kk < 4; ++kk) {
        float f[8];
#pragma unroll
        for (int j = 0; j < 8; ++j)
            f[j] = xs[(kk * 32 + quad * 8 + j) * 36 + nt * 16 + c];
        u32x4 u = {pack2bf(f[0], f[1]), pack2bf(f[2], f[3]),
                   pack2bf(f[4], f[5]), pack2bf(f[6], f[7])};
        xf[kk] = __builtin_bit_cast(u16x8, u);
    }

    const unsigned short* W = (mat == 0) ? WqB : (mat == 1) ? WkB : WvB;
    const float* bias = (mat == 0) ? bq : (mat == 1) ? bk : bv;
    const float  sc   = (mat == 0) ? SCALE_QL : 1.0f;   // bias scale only
    // V' scale: w = mask * 2^-18 for this column
    const float  vwsc = (mat == 2) ? mask[b * NSEQ + col] * W_SCALE : 0.f;
    const int    g    = col >> 4;
    // rho-permuted k-slot for kv-column col
    const int    roff = ((col >> 2) & 1) * 32;
    const int    j7   = (col & 3) | (((col >> 3) & 1) << 2);

#pragma unroll
    for (int tt = 0; tt < 4; ++tt) {
        const int t = th * 4 + tt;
        f32x4 acc = {0.f, 0.f, 0.f, 0.f};
#pragma unroll
        for (int kk = 0; kk < 4; ++kk)
            acc = mfma16(*reinterpret_cast<const u16x8*>(
                             W + (t * 16 + c) * DM + kk * 32 + quad * 8),
                         xf[kk], acc);
        if (mat == 2) {
            unsigned short* vwp = VW2 +
                (((size_t)((b * NH + t) * 128 + g)) << 9) + j7;
#pragma unroll
            for (int r = 0; r < 4; ++r)
                vwp[(quad * 4 + r + roff) * 8] =
                    f2bf((acc[r] + bias[t * 16 + quad * 4 + r]) * vwsc);
        } else {
            u16x4 pk;
#pragma unroll
            for (int r = 0; r < 4; ++r)
                pk[r] = f2bf(acc[r] + bias[t * 16 + quad * 4 + r] * sc);
            *reinterpret_cast<u16x4*>(
                (mat == 0 ? Q : Kb) + ((size_t)(b * NH + t) * NSEQ + col) * DK +
                quad * 4) = pk;
        }
    }
}

// ---------------------------------------------------------------------------
// k_attn: fixed-scale flash attention, register-resident, SOFTWARE-PIPELINED
// (round-10 structure, correctness-proven there). ROUND-11 CHANGE:
// __launch_bounds__(256, 3) -> 170-VGPR budget. Round 10 proved the
// pipeline's liveness (~130 regs) overflows the 128-reg budget of (,4):
// WRITE_SIZE 2 -> 22 MB of scratch spill, +12 us. This round trades one
// block/CU of occupancy (16 -> 12 waves, weak marginal value per rounds
// 1-4) for a spill-free deep pipeline (intra-wave overlap of
// QK / exp2+pack / PV across stages).
// 16 stages of 32 kv; stage s: QK(s+1) || PV(s) with B-frags packed last
// stage; exp2/pack(s+1) under PV; nk 2-deep, va 1-deep prefetch.
// rho-absorbed A-tile (round 9): zero DS ops / shuffles in the loop.
// Two q-tiles per block (round 8); l = PV C-row 16. Tripwire: WRITE_SIZE.
// ---------------------------------------------------------------------------
__global__ __launch_bounds__(256, 3) void k_attn(
    const unsigned short* __restrict__ Q,
    const unsigned short* __restrict__ Kb,
    const unsigned short* __restrict__ VW2,
    unsigned short* __restrict__ AO)
{
    __shared__ __align__(16) float smem[256 + 2 * 4 * 32 * 20];  // Lsm + Osm
    const int tid  = threadIdx.x;
    const int lane = tid & 63;
    const int w    = tid >> 6;      // kv quarter
    const int q32  = lane & 31;
    const int hi   = lane >> 5;

    // XCD-chunked swizzle: 1024 blocks -> 128-block chunk per XCD
    const int bid = ((int)blockIdx.x & 7) * 128 + ((int)blockIdx.x >> 3);
    const int b  = bid >> 8;
    const int h  = (bid >> 5) & 7;
    const int n0 = (bid & 31) << 6;     // 64-query tile
    const int bh = b * NH + h;

    // Q B-frags for the two 32-query sub-tiles (prescaled to log2 domain)
    const u16x8 uqA = *reinterpret_cast<const u16x8*>(
        Q + ((size_t)bh * NSEQ + n0 + q32) * DK + 8 * hi);
    const u16x8 uqB = *reinterpret_cast<const u16x8*>(
        Q + ((size_t)bh * NSEQ + n0 + 32 + q32) * DK + 8 * hi);

    const unsigned short* Kp = Kb + (size_t)bh * NSEQ * DK + 8 * hi;
    const unsigned short* Ap = VW2 + (((size_t)bh * 128) << 9) + lane * 8;

    f32x16 accA = {};                 // O^T rows 0-15, l at row 16 (tile A)
    f32x16 accB = {};                 // (tile B)
    const f32x16 z16 = {};
    const int kvb = w * (NSEQ / 4);   // 512-kv quarter
    const int gb  = kvb >> 4;         // first group of this quarter

    // ---- pipeline prologue: nk for blocks 0/1, bf + va for stage 0 ----
    u16x8 nkE = *reinterpret_cast<const u16x8*>(Kp + (size_t)(kvb + q32) * DK);
    u16x8 nkO = *reinterpret_cast<const u16x8*>(Kp + (size_t)(kvb + 32 + q32) * DK);
    u16x8 bfEA1, bfEA2, bfEB1, bfEB2;  // stage-s (even) B-frags
    u16x8 vaE0, vaE1;                  // stage-s (even) A-frags
    {
        __builtin_amdgcn_s_setprio(1);
        f32x16 SA = mfma32(nkE, uqA, z16);
        f32x16 SB = mfma32(nkE, uqB, z16);
        __builtin_amdgcn_s_setprio(0);
        nkE = *reinterpret_cast<const u16x8*>(Kp + (size_t)(kvb + 64 + q32) * DK);
        exppack(SA, bfEA1, bfEA2);
        exppack(SB, bfEB1, bfEB2);
    }
    vaE0 = *reinterpret_cast<const u16x8*>(Ap + ((size_t)gb << 9));
    vaE1 = *reinterpret_cast<const u16x8*>(Ap + ((size_t)(gb + 1) << 9));

#pragma unroll 1
    for (int it = 0; it < 8; ++it) {
        const int kvs = kvb + it * 64;     // even stage (s=2it) kv base
        const int g0  = gb + it * 4;       // even stage group

        // ===== even stage s=2it: QK(s+1) || PV(s), then pack(s+1) =====
        u16x8 bfOA1, bfOA2, bfOB1, bfOB2, vaO0, vaO1;
        {
            __builtin_amdgcn_s_setprio(1);
            f32x16 SA = mfma32(nkO, uqA, z16);     // QK stage s+1 (block 2it+1)
            accA = mfma32(vaE0, bfEA1, accA);      // PV stage s
            accB = mfma32(vaE0, bfEB1, accB);
            accA = mfma32(vaE1, bfEA2, accA);
            accB = mfma32(vaE1, bfEB2, accB);
            __builtin_amdgcn_s_setprio(0);
            exppack(SA, bfOA1, bfOA2);
            __builtin_amdgcn_s_setprio(1);
            f32x16 SB = mfma32(nkO, uqB, z16);
            __builtin_amdgcn_s_setprio(0);
            if (it < 7)                            // refill block 2it+3
                nkO = *reinterpret_cast<const u16x8*>(
                    Kp + (size_t)(kvs + 96 + q32) * DK);
            exppack(SB, bfOB1, bfOB2);
            vaO0 = *reinterpret_cast<const u16x8*>(Ap + ((size_t)(g0 + 2) << 9));
            vaO1 = *reinterpret_cast<const u16x8*>(Ap + ((size_t)(g0 + 3) << 9));
        }

        // ===== odd stage s=2it+1: QK(s+1) || PV(s), then pack(s+1) =====
        {
            __builtin_amdgcn_s_setprio(1);
            f32x16 SA;
            if (it < 7) SA = mfma32(nkE, uqA, z16); // QK stage s+1 (block 2it+2)
            accA = mfma32(vaO0, bfOA1, accA);       // PV stage s
            accB = mfma32(vaO0, bfOB1, accB);
            accA = mfma32(vaO1, bfOA2, accA);
            accB = mfma32(vaO1, bfOB2, accB);
            __builtin_amdgcn_s_setprio(0);
            if (it < 7) {
                exppack(SA, bfEA1, bfEA2);
                __builtin_amdgcn_s_setprio(1);
                f32x16 SB = mfma32(nkE, uqB, z16);
                __builtin_amdgcn_s_setprio(0);
                if (it < 6)                         // refill block 2it+4
                    nkE = *reinterpret_cast<const u16x8*>(
                        Kp + (size_t)(kvs + 128 + q32) * DK);
                exppack(SB, bfEB1, bfEB2);
                vaE0 = *reinterpret_cast<const u16x8*>(Ap + ((size_t)(g0 + 4) << 9));
                vaE1 = *reinterpret_cast<const u16x8*>(Ap + ((size_t)(g0 + 5) << 9));
            }
        }
    }

    // ---- 4-wave merge, two tiles ----
    // acc layout: col q=q32; hi=0 regs: dk 0-3 (r0-3), dk 8-11 (r4-7), l (r8)
    //             hi=1 regs: dk 4-7 (r0-3), dk 12-15 (r4-7)
    float* Lsm = smem;            // [t2][w][32]
    float* Osm = smem + 256;      // [t2][w][q*20 + dk], tile stride 2560
    {
        float* Orow = Osm + w * 640 + q32 * 20;
        *reinterpret_cast<f32x4*>(Orow + (hi ? 4 : 0)) =
            f32x4{accA[0], accA[1], accA[2], accA[3]};
        *reinterpret_cast<f32x4*>(Orow + (hi ? 12 : 8)) =
            f32x4{accA[4], accA[5], accA[6], accA[7]};
        if (!hi) Lsm[w * 32 + q32] = accA[8];
        float* Orow2 = Orow + 2560;
        *reinterpret_cast<f32x4*>(Orow2 + (hi ? 4 : 0)) =
            f32x4{accB[0], accB[1], accB[2], accB[3]};
        *reinterpret_cast<f32x4*>(Orow2 + (hi ? 12 : 8)) =
            f32x4{accB[4], accB[5], accB[6], accB[7]};
        if (!hi) Lsm[128 + w * 32 + q32] = accB[8];
    }
    __syncthreads();

    const int q   = tid >> 3;              // 0..31
    const int dk2 = (tid & 7) * 2;         // 0,2,..,14
#pragma unroll
    for (int t2 = 0; t2 < 2; ++t2) {
        const float* Lt = Lsm + t2 * 128;
        const float l = Lt[q] + Lt[32 + q] + Lt[64 + q] + Lt[96 + q];
        const float* Oq = Osm + t2 * 2560 + q * 20 + dk2;
        const float v0 = Oq[0] + Oq[640] + Oq[1280] + Oq[1920];
        const float v1 = Oq[1] + Oq[641] + Oq[1281] + Oq[1921];
        const float inv = 1.0f / l;
        *reinterpret_cast<unsigned int*>(
            AO + ((size_t)(b * NSEQ) + n0 + t2 * 32 + q) * DM + h * DK + dk2) =
            pack2bf(v0 * inv, v1 * inv);
    }
}

// ---------------------------------------------------------------------------
// k_fc: C^T-form FC, output directly in (B, D, N).
// grid = b(4) x n-tile(128) x t-half(2), 4 waves, wave = one d'-tile.
// ---------------------------------------------------------------------------
__global__ __launch_bounds__(256) void k_fc(
    const unsigned short* __restrict__ AO,
    const unsigned short* __restrict__ WfcB, const float* __restrict__ bfc,
    float* __restrict__ out)
{
    const int lane = threadIdx.x & 63;
    const int w    = threadIdx.x >> 6;
    const int c    = lane & 15;
    const int quad = lane >> 4;
    const int b    = blockIdx.x >> 8;
    const int n0   = ((blockIdx.x >> 1) & 127) << 4;
    const int t    = (blockIdx.x & 1) * 4 + w;

    u16x8 af[4];
#pragma unroll
    for (int kk = 0; kk < 4; ++kk)
        af[kk] = *reinterpret_cast<const u16x8*>(
            AO + ((size_t)(b * NSEQ) + n0 + c) * DM + kk * 32 + quad * 8);

    f32x4 acc = {0.f, 0.f, 0.f, 0.f};
#pragma unroll
    for (int kk = 0; kk < 4; ++kk)
        acc = mfma16(*reinterpret_cast<const u16x8*>(
                         WfcB + (t * 16 + c) * DM + kk * 32 + quad * 8),
                     af[kk], acc);
#pragma unroll
    for (int r = 0; r < 4; ++r)
        out[(size_t)(b * DM + t * 16 + quad * 4 + r) * NSEQ + n0 + c] =
            acc[r] + bfc[t * 16 + quad * 4 + r];
}

// ---------------------------------------------------------------------------
extern "C" void kernel_launch(void* const* d_in, const int* in_sizes, int n_in,
                              void* d_out, int out_size, void* d_ws, size_t ws_size,
                              hipStream_t stream)
{
    const float* x    = (const float*)d_in[0];
    const float* mask = (const float*)d_in[1];
    const float* Wq   = (const float*)d_in[2];
    const float* bq   = (const float*)d_in[3];
    const float* Wk   = (const float*)d_in[4];
    const float* bk   = (const float*)d_in[5];
    const float* Wv   = (const float*)d_in[6];
    const float* bv   = (const float*)d_in[7];
    const float* Wfc  = (const float*)d_in[8];
    const float* bfc  = (const float*)d_in[9];
    float* out = (float*)d_out;

    const size_t QKV_ELEMS = (size_t)BSZ * NH * NSEQ * DK;  // 1,048,576
    unsigned short* Q    = (unsigned short*)d_ws;
    unsigned short* Kb   = Q + QKV_ELEMS;
    unsigned short* AO   = Kb + QKV_ELEMS;
    unsigned short* WfcB = AO + QKV_ELEMS;
    unsigned short* VW2  = WfcB + DM * DM;   // [bh][g=128][lane=64][8] bf16
    unsigned short* WqB  = VW2 + (size_t)BSZ * NH * 128 * 512;
    unsigned short* WkB  = WqB + DM * DM;
    unsigned short* WvB  = WkB + DM * DM;

    k_prep<<<96, 256, 0, stream>>>(Wq, Wk, Wv, Wfc, mask,
                                   WqB, WkB, WvB, WfcB, VW2);
    k_qkv<<<256, 768, 0, stream>>>(x, WqB, bq, WkB, bk, WvB, bv, mask,
                                   Q, Kb, VW2);
    k_attn<<<1024, 256, 0, stream>>>(Q, Kb, VW2, AO);
    k_fc<<<1024, 256, 0, stream>>>(AO, WfcB, bfc, out);
}

// Round 12
// 117.115 us; speedup vs baseline: 1.0814x; 1.0086x over previous
//
#include <hip/hip_runtime.h>
#include <stdint.h>

#define BSZ  4
#define NSEQ 2048
#define DM   128
#define NH   8
#define DK   16
#define LOG2E 1.4426950408889634f
// LOG2E / sqrt(128): folded into Wq/bq so scores exit QK^T in log2 domain
#define SCALE_QL 0.1275156338341935f
// mask weight: w = mask * 2^-18 (exact in bf16); folded into V' and the
// l-row of the PV A-tile. p = exp2(S) stays <= ~2^10, l ~ 1e-2 -> safe fp32.
#define W_SCALE 3.814697265625e-6f

typedef __bf16          bf16x8v __attribute__((ext_vector_type(8)));
typedef float           f32x4   __attribute__((ext_vector_type(4)));
typedef float           f32x16  __attribute__((ext_vector_type(16)));
typedef unsigned short  u16x8   __attribute__((ext_vector_type(8)));
typedef unsigned short  u16x4   __attribute__((ext_vector_type(4)));
typedef unsigned int    u32x2   __attribute__((ext_vector_type(2)));
typedef unsigned int    u32x4   __attribute__((ext_vector_type(4)));

__device__ __forceinline__ unsigned short f2bf(float f) {
    unsigned u = __float_as_uint(f);
    u = (u + 0x7fffu + ((u >> 16) & 1u)) >> 16;
    return (unsigned short)u;
}

__device__ __forceinline__ unsigned int pack2bf(float a, float b) {
#if __has_builtin(__builtin_amdgcn_cvt_pk_bf16_f32)
    typedef __bf16 bf16x2 __attribute__((ext_vector_type(2)));
    bf16x2 v = __builtin_amdgcn_cvt_pk_bf16_f32(a, b);
    return __builtin_bit_cast(unsigned int, v);
#else
    return (unsigned)f2bf(a) | ((unsigned)f2bf(b) << 16);
#endif
}

__device__ __forceinline__ float exp2_(float x) {
#if __has_builtin(__builtin_amdgcn_exp2f)
    return __builtin_amdgcn_exp2f(x);
#else
    return exp2f(x);
#endif
}

__device__ __forceinline__ f32x4 mfma16(u16x8 a, u16x8 b, f32x4 c) {
    return __builtin_amdgcn_mfma_f32_16x16x32_bf16(
        __builtin_bit_cast(bf16x8v, a), __builtin_bit_cast(bf16x8v, b), c, 0, 0, 0);
}
__device__ __forceinline__ f32x16 mfma32(u16x8 a, u16x8 b, f32x16 c) {
    return __builtin_amdgcn_mfma_f32_32x32x16_bf16(
        __builtin_bit_cast(bf16x8v, a), __builtin_bit_cast(bf16x8v, b), c, 0, 0, 0);
}

// ROUND-9 (final): shuffle-free P->B-frag. Packing S regs 0..7 / 8..15
// straight into B-frags induces the fixed k-slot->kv involution
//   rho = [0,1,2,3, 8,9,10,11, 4,5,6,7, 12,13,14,15]
// which is pre-absorbed into the PV A-tile by k_qkv/k_prep.
// Result: zero DS ops and zero cndmasks in the attention main loop.
__device__ __forceinline__ void build_bfrags(const f32x16& S, u16x8& bfe, u16x8& bfo) {
    const u32x4 f1 = {pack2bf(S[0],  S[1]),  pack2bf(S[2],  S[3]),
                      pack2bf(S[4],  S[5]),  pack2bf(S[6],  S[7])};
    const u32x4 f2 = {pack2bf(S[8],  S[9]),  pack2bf(S[10], S[11]),
                      pack2bf(S[12], S[13]), pack2bf(S[14], S[15])};
    bfe = __builtin_bit_cast(u16x8, f1);
    bfo = __builtin_bit_cast(u16x8, f2);
}

// ---------------------------------------------------------------------------
// k_prep: one-shot weight conversion + mask weave. Converts Wq (pre-scaled
// to log2 domain), Wk, Wv, Wfc to bf16 once, and weaves w = bf16(mask*2^-18)
// into VW2 row 16 at rho-permuted k-slots. grid = 96 x 256.
// ---------------------------------------------------------------------------
__global__ __launch_bounds__(256) void k_prep(
    const float* __restrict__ Wq, const float* __restrict__ Wk,
    const float* __restrict__ Wv, const float* __restrict__ Wfc,
    const float* __restrict__ mask,
    unsigned short* __restrict__ WqB, unsigned short* __restrict__ WkB,
    unsigned short* __restrict__ WvB, unsigned short* __restrict__ WfcB,
    unsigned short* __restrict__ VW2)
{
    const int gt = blockIdx.x * 256 + threadIdx.x;
    if (gt < DM * DM) {
        WqB[gt]  = f2bf(Wq[gt] * SCALE_QL);
        WkB[gt]  = f2bf(Wk[gt]);
        WvB[gt]  = f2bf(Wv[gt]);
        WfcB[gt] = f2bf(Wfc[gt]);
    } else if (gt < DM * DM + BSZ * NSEQ) {
        const int i  = gt - DM * DM;          // i = b*NSEQ + kv
        const int kv = i & (NSEQ - 1);
        const int bb = i >> 11;
        const unsigned short w16 = f2bf(mask[i] * W_SCALE);
        // rho-permuted k-slot: khalf=(kv>>2)&1, j=(kv&3)+4*((kv>>3)&1)
        unsigned short* dst = VW2 +
            (((size_t)(bb * NH) * 128 + (kv >> 4)) << 9) +
            (16 + ((kv >> 2) & 1) * 32) * 8 + (kv & 3) + 4 * ((kv >> 3) & 1);
#pragma unroll
        for (int hh = 0; hh < NH; ++hh)
            dst[(size_t)hh * 128 * 512] = w16;
    }
}

// ---------------------------------------------------------------------------
// k_qkv: C^T-form projection, x-tile staged in LDS (coalesced f32x4 loads).
// grid = b(4) x n-tile32(64), 768 threads = 12 waves = mat(3) x nsub(2) x th(2).
// W pre-converted bf16 (k_prep). Q,K -> [B][H][N][16] bf16.
// V is emitted directly as the PV A-tile VW2[bh][g=kv/16][lane][8] with the
// rho column permutation: k-slot of column o: khalf=(o>>2)&1 (lane =
// row + 32*khalf), j=(o&3)+4*((o>>3)&1). Rows 0-15 = V' (V scaled by
// w=mask*2^-18), row 16 = w (k_prep), rows 17-31 = garbage (C rows unread).
// ---------------------------------------------------------------------------
__global__ __launch_bounds__(768) void k_qkv(
    const float* __restrict__ x,
    const unsigned short* __restrict__ WqB, const float* __restrict__ bq,
    const unsigned short* __restrict__ WkB, const float* __restrict__ bk,
    const unsigned short* __restrict__ WvB, const float* __restrict__ bv,
    const float* __restrict__ mask,
    unsigned short* __restrict__ Q, unsigned short* __restrict__ Kb,
    unsigned short* __restrict__ VW2)
{
    __shared__ __align__(16) float xs[DM * 36];   // 32 n + 4 pad
    const int tid = threadIdx.x;

    const int b  = blockIdx.x >> 6;
    const int n0 = (blockIdx.x & 63) << 5;

    // stage x[b][0..128][n0..n0+32] -> xs[d*36 + j], fully coalesced
#pragma unroll
    for (int i = tid; i < 1024; i += 768) {
        const int d = i >> 3, c4 = (i & 7) << 2;
        *reinterpret_cast<f32x4*>(&xs[d * 36 + c4]) =
            *reinterpret_cast<const f32x4*>(x + (size_t)(b * DM + d) * NSEQ + n0 + c4);
    }
    __syncthreads();

    const int lane = tid & 63;
    const int wv   = tid >> 6;          // 0..11
    const int mat  = wv >> 2;           // 0..2
    const int nt   = (wv >> 1) & 1;     // n subtile
    const int th   = wv & 1;            // t half
    const int c    = lane & 15;
    const int quad = lane >> 4;
    const int col  = n0 + nt * 16 + c;

    // B-frag from LDS: B[k=d][n=c]
    u16x8 xf[4];
#pragma unroll
    for (int kk = 0; kk < 4; ++kk) {
        float f[8];
#pragma unroll
        for (int j = 0; j < 8; ++j)
            f[j] = xs[(kk * 32 + quad * 8 + j) * 36 + nt * 16 + c];
        u32x4 u = {pack2bf(f[0], f[1]), pack2bf(f[2], f[3]),
                   pack2bf(f[4], f[5]), pack2bf(f[6], f[7])};
        xf[kk] = __builtin_bit_cast(u16x8, u);
    }

    const unsigned short* W = (mat == 0) ? WqB : (mat == 1) ? WkB : WvB;
    const float* bias = (mat == 0) ? bq : (mat == 1) ? bk : bv;
    const float  sc   = (mat == 0) ? SCALE_QL : 1.0f;   // bias scale only
    // V' scale: w = mask * 2^-18 for this column
    const float  vwsc = (mat == 2) ? mask[b * NSEQ + col] * W_SCALE : 0.f;
    const int    g    = col >> 4;
    // rho-permuted k-slot for kv-column col
    const int    roff = ((col >> 2) & 1) * 32;
    const int    j7   = (col & 3) | (((col >> 3) & 1) << 2);

#pragma unroll
    for (int tt = 0; tt < 4; ++tt) {
        const int t = th * 4 + tt;
        f32x4 acc = {0.f, 0.f, 0.f, 0.f};
#pragma unroll
        for (int kk = 0; kk < 4; ++kk)
            acc = mfma16(*reinterpret_cast<const u16x8*>(
                             W + (t * 16 + c) * DM + kk * 32 + quad * 8),
                         xf[kk], acc);
        if (mat == 2) {
            unsigned short* vwp = VW2 +
                (((size_t)((b * NH + t) * 128 + g)) << 9) + j7;
#pragma unroll
            for (int r = 0; r < 4; ++r)
                vwp[(quad * 4 + r + roff) * 8] =
                    f2bf((acc[r] + bias[t * 16 + quad * 4 + r]) * vwsc);
        } else {
            u16x4 pk;
#pragma unroll
            for (int r = 0; r < 4; ++r)
                pk[r] = f2bf(acc[r] + bias[t * 16 + quad * 4 + r] * sc);
            *reinterpret_cast<u16x4*>(
                (mat == 0 ? Q : Kb) + ((size_t)(b * NH + t) * NSEQ + col) * DK +
                quad * 4) = pk;
        }
    }
}

// ---------------------------------------------------------------------------
// k_attn: fixed-scale flash attention, fully register-resident main loop.
// FINAL (round-9 structure, best measured: total 115.96 us). S regs pack
// STRAIGHT into B-frags (8 cvt_pk per tile, no ds_bpermute, no cndmask);
// the k-slot->kv involution rho is pre-absorbed into the VW2 A-tile.
// Main loop has ZERO DS ops. Two query-tiles per block (round 8): grid
// 1024 = 4 blocks/CU, shared nk/va across streams. l falls out of PV
// C-row 16 (w row in A-tile). LDS (21.5 KB) only for the epilogue merge.
// __launch_bounds__(256,4): proven no-spill regime.
// Post-mortem R10/R11: deeper software pipelining either spills (128-reg
// budget) or costs a block of occupancy (3 blocks/CU) — both slower than
// this simple loop. Scheduling design space on this structure exhausted.
// ---------------------------------------------------------------------------
__global__ __launch_bounds__(256, 4) void k_attn(
    const unsigned short* __restrict__ Q,
    const unsigned short* __restrict__ Kb,
    const unsigned short* __restrict__ VW2,
    unsigned short* __restrict__ AO)
{
    __shared__ __align__(16) float smem[256 + 2 * 4 * 32 * 20];  // Lsm + Osm
    const int tid  = threadIdx.x;
    const int lane = tid & 63;
    const int w    = tid >> 6;      // kv quarter
    const int q32  = lane & 31;
    const int hi   = lane >> 5;

    // XCD-chunked swizzle: 1024 blocks -> 128-block chunk per XCD
    // (= 4 complete (b,h) groups of 32 blocks each).
    const int bid = ((int)blockIdx.x & 7) * 128 + ((int)blockIdx.x >> 3);
    const int b  = bid >> 8;
    const int h  = (bid >> 5) & 7;
    const int n0 = (bid & 31) << 6;     // 64-query tile
    const int bh = b * NH + h;

    // Q B-frags for the two 32-query sub-tiles (prescaled to log2 domain)
    const u16x8 uqA = *reinterpret_cast<const u16x8*>(
        Q + ((size_t)bh * NSEQ + n0 + q32) * DK + 8 * hi);
    const u16x8 uqB = *reinterpret_cast<const u16x8*>(
        Q + ((size_t)bh * NSEQ + n0 + 32 + q32) * DK + 8 * hi);

    const unsigned short* Kp = Kb + (size_t)bh * NSEQ * DK + 8 * hi;
    // PV A-tile: lane-linear, 16 B/lane fully coalesced
    const unsigned short* Ap = VW2 + (((size_t)bh * 128) << 9) + lane * 8;

    f32x16 accA = {};                 // O^T rows 0-15, l at row 16 (tile A)
    f32x16 accB = {};                 // (tile B)
    const f32x16 z16 = {};
    const int kvb = w * (NSEQ / 4);

    // prefetch iteration 0's K fragments
    u16x8 nk0 = *reinterpret_cast<const u16x8*>(Kp + (size_t)(kvb + q32) * DK);
    u16x8 nk1 = *reinterpret_cast<const u16x8*>(Kp + (size_t)(kvb + 32 + q32) * DK);

#pragma unroll 1
    for (int it = 0; it < 8; ++it) {
        const int kv0 = kvb + it * 64;
        const int g0  = kv0 >> 4;
        // PV A-frags for this iter's 4 K=16 tiles (L2-resident, shared A/B)
        const u16x8 va0 = *reinterpret_cast<const u16x8*>(Ap + ((size_t)(g0    ) << 9));
        const u16x8 va1 = *reinterpret_cast<const u16x8*>(Ap + ((size_t)(g0 + 1) << 9));
        const u16x8 va2 = *reinterpret_cast<const u16x8*>(Ap + ((size_t)(g0 + 2) << 9));
        const u16x8 va3 = *reinterpret_cast<const u16x8*>(Ap + ((size_t)(g0 + 3) << 9));

        // --- kv [kv0, kv0+32): two independent S-streams off nk0 ---
        {
            __builtin_amdgcn_s_setprio(1);
            f32x16 SA = mfma32(nk0, uqA, z16);   // S^T[kv][q] (log2 domain)
            f32x16 SB = mfma32(nk0, uqB, z16);
            __builtin_amdgcn_s_setprio(0);
            if (it < 7)
                nk0 = *reinterpret_cast<const u16x8*>(
                    Kp + (size_t)(kv0 + 64 + q32) * DK);
#pragma unroll
            for (int i = 0; i < 16; ++i) SA[i] = exp2_(SA[i]);
#pragma unroll
            for (int i = 0; i < 16; ++i) SB[i] = exp2_(SB[i]);
            u16x8 bfA1, bfA2, bfB1, bfB2;
            build_bfrags(SA, bfA1, bfA2);
            build_bfrags(SB, bfB1, bfB2);
            __builtin_amdgcn_s_setprio(1);
            accA = mfma32(va0, bfA1, accA);
            accB = mfma32(va0, bfB1, accB);
            accA = mfma32(va1, bfA2, accA);
            accB = mfma32(va1, bfB2, accB);
            __builtin_amdgcn_s_setprio(0);
        }

        // --- kv [kv0+32, kv0+64): same off nk1 ---
        {
            __builtin_amdgcn_s_setprio(1);
            f32x16 SA = mfma32(nk1, uqA, z16);
            f32x16 SB = mfma32(nk1, uqB, z16);
            __builtin_amdgcn_s_setprio(0);
            if (it < 7)
                nk1 = *reinterpret_cast<const u16x8*>(
                    Kp + (size_t)(kv0 + 96 + q32) * DK);
#pragma unroll
            for (int i = 0; i < 16; ++i) SA[i] = exp2_(SA[i]);
#pragma unroll
            for (int i = 0; i < 16; ++i) SB[i] = exp2_(SB[i]);
            u16x8 bfA1, bfA2, bfB1, bfB2;
            build_bfrags(SA, bfA1, bfA2);
            build_bfrags(SB, bfB1, bfB2);
            __builtin_amdgcn_s_setprio(1);
            accA = mfma32(va2, bfA1, accA);
            accB = mfma32(va2, bfB1, accB);
            accA = mfma32(va3, bfA2, accA);
            accB = mfma32(va3, bfB2, accB);
            __builtin_amdgcn_s_setprio(0);
        }
    }

    // ---- 4-wave merge, two tiles ----
    // acc layout: col q=q32; hi=0 regs: dk 0-3 (r0-3), dk 8-11 (r4-7), l (r8)
    //             hi=1 regs: dk 4-7 (r0-3), dk 12-15 (r4-7)
    float* Lsm = smem;            // [t2][w][32]
    float* Osm = smem + 256;      // [t2][w][q*20 + dk], tile stride 2560
    {
        float* Orow = Osm + w * 640 + q32 * 20;
        *reinterpret_cast<f32x4*>(Orow + (hi ? 4 : 0)) =
            f32x4{accA[0], accA[1], accA[2], accA[3]};
        *reinterpret_cast<f32x4*>(Orow + (hi ? 12 : 8)) =
            f32x4{accA[4], accA[5], accA[6], accA[7]};
        if (!hi) Lsm[w * 32 + q32] = accA[8];
        float* Orow2 = Orow + 2560;
        *reinterpret_cast<f32x4*>(Orow2 + (hi ? 4 : 0)) =
            f32x4{accB[0], accB[1], accB[2], accB[3]};
        *reinterpret_cast<f32x4*>(Orow2 + (hi ? 12 : 8)) =
            f32x4{accB[4], accB[5], accB[6], accB[7]};
        if (!hi) Lsm[128 + w * 32 + q32] = accB[8];
    }
    __syncthreads();

    const int q   = tid >> 3;              // 0..31
    const int dk2 = (tid & 7) * 2;         // 0,2,..,14
#pragma unroll
    for (int t2 = 0; t2 < 2; ++t2) {
        const float* Lt = Lsm + t2 * 128;
        const float l = Lt[q] + Lt[32 + q] + Lt[64 + q] + Lt[96 + q];
        const float* Oq = Osm + t2 * 2560 + q * 20 + dk2;
        const float v0 = Oq[0] + Oq[640] + Oq[1280] + Oq[1920];
        const float v1 = Oq[1] + Oq[641] + Oq[1281] + Oq[1921];
        const float inv = 1.0f / l;
        *reinterpret_cast<unsigned int*>(
            AO + ((size_t)(b * NSEQ) + n0 + t2 * 32 + q) * DM + h * DK + dk2) =
            pack2bf(v0 * inv, v1 * inv);
    }
}

// ---------------------------------------------------------------------------
// k_fc: C^T-form FC, output directly in (B, D, N).
// grid = b(4) x n-tile(128) x t-half(2), 4 waves, wave = one d'-tile.
// ---------------------------------------------------------------------------
__global__ __launch_bounds__(256) void k_fc(
    const unsigned short* __restrict__ AO,
    const unsigned short* __restrict__ WfcB, const float* __restrict__ bfc,
    float* __restrict__ out)
{
    const int lane = threadIdx.x & 63;
    const int w    = threadIdx.x >> 6;
    const int c    = lane & 15;
    const int quad = lane >> 4;
    const int b    = blockIdx.x >> 8;
    const int n0   = ((blockIdx.x >> 1) & 127) << 4;
    const int t    = (blockIdx.x & 1) * 4 + w;

    u16x8 af[4];
#pragma unroll
    for (int kk = 0; kk < 4; ++kk)
        af[kk] = *reinterpret_cast<const u16x8*>(
            AO + ((size_t)(b * NSEQ) + n0 + c) * DM + kk * 32 + quad * 8);

    f32x4 acc = {0.f, 0.f, 0.f, 0.f};
#pragma unroll
    for (int kk = 0; kk < 4; ++kk)
        acc = mfma16(*reinterpret_cast<const u16x8*>(
                         WfcB + (t * 16 + c) * DM + kk * 32 + quad * 8),
                     af[kk], acc);
#pragma unroll
    for (int r = 0; r < 4; ++r)
        out[(size_t)(b * DM + t * 16 + quad * 4 + r) * NSEQ + n0 + c] =
            acc[r] + bfc[t * 16 + quad * 4 + r];
}

// ---------------------------------------------------------------------------
extern "C" void kernel_launch(void* const* d_in, const int* in_sizes, int n_in,
                              void* d_out, int out_size, void* d_ws, size_t ws_size,
                              hipStream_t stream)
{
    const float* x    = (const float*)d_in[0];
    const float* mask = (const float*)d_in[1];
    const float* Wq   = (const float*)d_in[2];
    const float* bq   = (const float*)d_in[3];
    const float* Wk   = (const float*)d_in[4];
    const float* bk   = (const float*)d_in[5];
    const float* Wv   = (const float*)d_in[6];
    const float* bv   = (const float*)d_in[7];
    const float* Wfc  = (const float*)d_in[8];
    const float* bfc  = (const float*)d_in[9];
    float* out = (float*)d_out;

    const size_t QKV_ELEMS = (size_t)BSZ * NH * NSEQ * DK;  // 1,048,576
    unsigned short* Q    = (unsigned short*)d_ws;
    unsigned short* Kb   = Q + QKV_ELEMS;
    unsigned short* AO   = Kb + QKV_ELEMS;
    unsigned short* WfcB = AO + QKV_ELEMS;
    unsigned short* VW2  = WfcB + DM * DM;   // [bh][g=128][lane=64][8] bf16
    unsigned short* WqB  = VW2 + (size_t)BSZ * NH * 128 * 512;
    unsigned short* WkB  = WqB + DM * DM;
    unsigned short* WvB  = WkB + DM * DM;

    k_prep<<<96, 256, 0, stream>>>(Wq, Wk, Wv, Wfc, mask,
                                   WqB, WkB, WvB, WfcB, VW2);
    k_qkv<<<256, 768, 0, stream>>>(x, WqB, bq, WkB, bk, WvB, bv, mask,
                                   Q, Kb, VW2);
    k_attn<<<1024, 256, 0, stream>>>(Q, Kb, VW2, AO);
    k_fc<<<1024, 256, 0, stream>>>(AO, WfcB, bfc, out);
}